// Round 1
// baseline (629.564 us; speedup 1.0000x reference)
//
#include <hip/hip_runtime.h>
#include <math.h>

#define NN 50000
#define NE 800000
#define DIM 128
#define NGR 128
#define SCAN_NB 196   // ceil(NN/256)

// ---- workspace layout (bytes) ----
#define OFF_FLAG    0
#define OFF_SCALE   1024
#define OFF_SHIFT   2048
#define OFF_GSTART  4096
#define OFF_BSUM    8192
#define OFF_BOFF    16384
#define OFF_PSUM    32768                  // 256*128*4 = 131072
#define OFF_PSQ     (32768+131072)         // ends 294912
#define OFF_W1LT    294912
#define OFF_W1RT    (294912+65536)
#define OFF_W2LT    (294912+131072)
#define OFF_W2RT    (294912+196608)
#define OFF_RO      (294912+262144)        // 557056, 64KB
#define OFF_DEG     1048576
#define OFF_RSTART  (1048576+262144)
#define OFF_CURSOR  (1310720+262144)
#define OFF_CSR     2097152                // 3.2MB
#define OFF_H0      6291456                // 25.6MB
#define OFF_AGG     33554432               // 25.6MB
#define OFF_H1      62914560               // 25.6MB (src32/dst32 alias here, freed before h1 written)
#define OFF_SRC32   62914560
#define OFF_DST32   (62914560+3200000)
#define WS_NEED     88514560

// detect int64 vs int32 index buffers: edge values are random in [0,50000),
// so 64 consecutive high words all-zero <=> int64 layout.
__global__ void probe_width(const unsigned* __restrict__ e, int* flag) {
  unsigned acc = 0;
  for (int i = 0; i < 64; ++i) acc |= e[2*i+1];
  *flag = (acc == 0) ? 1 : 0;
}

__global__ void convert_edges(const void* __restrict__ edge, const int* __restrict__ flag,
                              int* __restrict__ src, int* __restrict__ dst) {
  int e = blockIdx.x*blockDim.x + threadIdx.x;
  if (e >= NE) return;
  if (*flag) {
    const long long* p = (const long long*)edge;
    src[e] = (int)p[e];
    dst[e] = (int)p[NE + e];
  } else {
    const int* p = (const int*)edge;
    src[e] = p[e];
    dst[e] = p[NE + e];
  }
}

__global__ void transpose_w(const float* __restrict__ W, float* __restrict__ WT) {
  int i = blockIdx.x*blockDim.x + threadIdx.x;   // 16384 threads
  int j = i >> 7, k = i & 127;
  WT[k*DIM + j] = W[i];
}

__global__ void bn_stats(const float* __restrict__ x, float* __restrict__ psum,
                         float* __restrict__ psq) {
  int col  = threadIdx.x & 127;
  int half = threadIdx.x >> 7;
  float s = 0.f, q = 0.f;
  for (int r = blockIdx.x*2 + half; r < NN; r += 512) {
    float v = x[(size_t)r*DIM + col];
    s += v; q += v*v;
  }
  __shared__ float ss[128], sq[128];
  if (half) { ss[col] = s; sq[col] = q; }
  __syncthreads();
  if (!half) {
    psum[blockIdx.x*DIM + col] = s + ss[col];
    psq [blockIdx.x*DIM + col] = q + sq[col];
  }
}

__global__ void bn_final(const float* __restrict__ psum, const float* __restrict__ psq,
                         const float* __restrict__ gamma, const float* __restrict__ beta,
                         float* __restrict__ sc, float* __restrict__ sh) {
  int c = threadIdx.x;
  float s = 0.f, q = 0.f;
  for (int b = 0; b < 256; ++b) { s += psum[b*DIM+c]; q += psq[b*DIM+c]; }
  float mu  = s * (1.0f/NN);
  float var = q * (1.0f/NN) - mu*mu;     // biased variance
  float a = gamma[c] * rsqrtf(var + 1e-5f);
  sc[c] = a;
  sh[c] = beta[c] - mu*a;
}

__global__ void bn_apply(const float* __restrict__ x, const float* __restrict__ sc,
                         const float* __restrict__ sh, float* __restrict__ h0) {
  long i = (long)blockIdx.x*256 + threadIdx.x;
  if (i >= (long)NN*DIM/4) return;
  int c4 = (int)((i*4) & (DIM-1));
  float4 v = ((const float4*)x)[i];
  float4 r;
  r.x = v.x*sc[c4+0] + sh[c4+0];
  r.y = v.y*sc[c4+1] + sh[c4+1];
  r.z = v.z*sc[c4+2] + sh[c4+2];
  r.w = v.w*sc[c4+3] + sh[c4+3];
  ((float4*)h0)[i] = r;
}

__global__ void count_deg(const int* __restrict__ dst, int* __restrict__ deg) {
  int e = blockIdx.x*blockDim.x + threadIdx.x;
  if (e < NE) atomicAdd(&deg[dst[e]], 1);
}

__global__ void deg_bsum(const int* __restrict__ deg, int* __restrict__ bsum) {
  __shared__ int sm[256];
  int i = blockIdx.x*256 + threadIdx.x;
  sm[threadIdx.x] = (i < NN) ? deg[i] : 0;
  __syncthreads();
  for (int off = 128; off > 0; off >>= 1) {
    if (threadIdx.x < off) sm[threadIdx.x] += sm[threadIdx.x + off];
    __syncthreads();
  }
  if (threadIdx.x == 0) bsum[blockIdx.x] = sm[0];
}

__global__ void scan_bsum(const int* __restrict__ bsum, int* __restrict__ boff) {
  __shared__ int sm[256];
  int t = threadIdx.x;
  int v = (t < SCAN_NB) ? bsum[t] : 0;
  sm[t] = v;
  __syncthreads();
  for (int off = 1; off < 256; off <<= 1) {
    int xx = (t >= off) ? sm[t-off] : 0;
    __syncthreads();
    sm[t] += xx;
    __syncthreads();
  }
  if (t < SCAN_NB) boff[t] = sm[t] - v;   // exclusive
}

__global__ void scan_apply(const int* __restrict__ deg, const int* __restrict__ boff,
                           int* __restrict__ row_start, int* __restrict__ cursor) {
  __shared__ int sm[256];
  int t = threadIdx.x;
  int i = blockIdx.x*256 + t;
  int v = (i < NN) ? deg[i] : 0;
  sm[t] = v;
  __syncthreads();
  for (int off = 1; off < 256; off <<= 1) {
    int xx = (t >= off) ? sm[t-off] : 0;
    __syncthreads();
    sm[t] += xx;
    __syncthreads();
  }
  int ex = boff[blockIdx.x] + sm[t] - v;
  if (i < NN) { row_start[i] = ex; cursor[i] = ex; }
  if (i == NN-1) row_start[NN] = ex + v;  // == NE
}

__global__ void scatter_edges(const int* __restrict__ src, const int* __restrict__ dst,
                              int* __restrict__ cursor, int* __restrict__ csr_src) {
  int e = blockIdx.x*blockDim.x + threadIdx.x;
  if (e >= NE) return;
  int d = dst[e];
  int pos = atomicAdd(&cursor[d], 1);
  csr_src[pos] = src[e];
}

// one wave per node; lane covers 2 floats (float2) of the 128-dim row
__global__ void aggregate(const float* __restrict__ h, const int* __restrict__ row_start,
                          const int* __restrict__ csr_src, float* __restrict__ out) {
  int node = blockIdx.x*4 + (threadIdx.x >> 6);
  if (node >= NN) return;
  int lane = threadIdx.x & 63;
  int p0 = row_start[node], p1 = row_start[node+1];
  const float2* h2 = (const float2*)h;
  float ax = 0.f, ay = 0.f;
  for (int p = p0; p < p1; ++p) {
    int s = csr_src[p];
    float2 v = h2[(size_t)s*64 + lane];
    ax += v.x; ay += v.y;
  }
  int d = p1 - p0;
  float inv = 1.0f / (float)(d > 1 ? d : 1);
  float2 o; o.x = ax*inv; o.y = ay*inv;
  ((float2*)out)[(size_t)node*64 + lane] = o;
}

// h_out = ELU(agg @ Wl^T + b + root @ Wr^T)
// lane = node (64 nodes/block), wave jg computes output cols [jg*32, jg*32+32)
// inputs staged transposed in LDS (per-lane reads); weights read at wave-uniform
// addresses (scalar/broadcast path) so the LDS pipe stays un-contended.
__global__ __launch_bounds__(256) void sage_linear(
    const float* __restrict__ root, const float* __restrict__ agg,
    const float* __restrict__ WlT, const float* __restrict__ bias,
    const float* __restrict__ WrT, float* __restrict__ out) {
  __shared__ float sA[DIM*65];
  __shared__ float sR[DIM*65];
  int n0 = blockIdx.x * 64;
  int t = threadIdx.x;
  for (int idx = t; idx < 64*DIM; idx += 256) {
    int n = idx >> 7, k = idx & 127;
    int node = n0 + n;
    float va = 0.f, vr = 0.f;
    if (node < NN) { va = agg[(size_t)node*DIM + k]; vr = root[(size_t)node*DIM + k]; }
    sA[k*65 + n] = va;
    sR[k*65 + n] = vr;
  }
  __syncthreads();

  int lane = t & 63;
  int jb = __builtin_amdgcn_readfirstlane((t >> 6) * 32);
  float acc[32];
  #pragma unroll
  for (int j = 0; j < 32; ++j) acc[j] = bias[jb + j];

  for (int k = 0; k < DIM; ++k) {
    float a = sA[k*65 + lane];
    float r = sR[k*65 + lane];
    const float4* wl4 = (const float4*)(WlT + k*DIM + jb);
    const float4* wr4 = (const float4*)(WrT + k*DIM + jb);
    #pragma unroll
    for (int jj = 0; jj < 8; ++jj) {
      float4 wl = wl4[jj];
      float4 wr = wr4[jj];
      acc[4*jj+0] += wl.x*a + wr.x*r;
      acc[4*jj+1] += wl.y*a + wr.y*r;
      acc[4*jj+2] += wl.z*a + wr.z*r;
      acc[4*jj+3] += wl.w*a + wr.w*r;
    }
  }
  __syncthreads();
  #pragma unroll
  for (int j = 0; j < 32; ++j) {
    float v = acc[j];
    v = (v > 0.f) ? v : (expf(v) - 1.0f);   // ELU
    sA[lane*130 + jb + j] = v;              // transpose via LDS for coalesced store
  }
  __syncthreads();
  for (int idx = t; idx < 64*DIM; idx += 256) {
    int n = idx >> 7, j = idx & 127;
    int node = n0 + n;
    if (node < NN) out[(size_t)node*DIM + j] = sA[n*130 + j];
  }
}

__global__ void graph_bounds(const void* __restrict__ batch, const int* __restrict__ flag,
                             int* __restrict__ gstart) {
  int n = blockIdx.x*blockDim.x + threadIdx.x;
  if (n > NN) return;
  bool w = (*flag != 0);
  int bn = NGR, bp = -1;
  if (n < NN) bn = w ? (int)((const long long*)batch)[n]   : ((const int*)batch)[n];
  if (n > 0)  bp = w ? (int)((const long long*)batch)[n-1] : ((const int*)batch)[n-1];
  for (int g = bp + 1; g <= bn; ++g) gstart[g] = n;   // gstart[g] = lower_bound(batch, g)
}

__global__ void max_pool(const float* __restrict__ h, const int* __restrict__ gstart,
                         float* __restrict__ ro) {
  int g = blockIdx.x, c = threadIdx.x;
  int s = gstart[g], e = gstart[g+1];
  float m = -INFINITY;
  for (int n = s; n < e; ++n) m = fmaxf(m, h[(size_t)n*DIM + c]);
  ro[g*DIM + c] = m;
}

__global__ void classify(const float* __restrict__ ro,
                         const float* __restrict__ Wc1, const float* __restrict__ bc1,
                         const float* __restrict__ Wc2, const float* __restrict__ bc2,
                         float* __restrict__ out) {
  int g = blockIdx.x, t = threadIdx.x;   // 64 threads
  __shared__ float row[128];
  __shared__ float rv[64];
  row[t]      = ro[g*DIM + t];
  row[t + 64] = ro[g*DIM + 64 + t];
  __syncthreads();
  float acc = bc1[t];
  for (int k = 0; k < 128; ++k) acc += row[k] * Wc1[t*128 + k];
  rv[t] = acc;
  out[1280 + g*64 + t] = acc;            // rv output (second tuple element)
  __syncthreads();
  if (t < 10) {
    float o = bc2[t];
    for (int k = 0; k < 64; ++k) o += rv[k] * Wc2[t*64 + k];
    out[g*10 + t] = o;                   // logits (first tuple element)
  }
}

extern "C" void kernel_launch(void* const* d_in, const int* in_sizes, int n_in,
                              void* d_out, int out_size, void* d_ws, size_t ws_size,
                              hipStream_t stream) {
  const float* x     = (const float*)d_in[0];
  const void*  edge  = d_in[1];
  const void*  batch = d_in[2];
  const float* gamma = (const float*)d_in[3];
  const float* beta  = (const float*)d_in[4];
  const float* W1l   = (const float*)d_in[5];
  const float* b1    = (const float*)d_in[6];
  const float* W1r   = (const float*)d_in[7];
  const float* W2l   = (const float*)d_in[8];
  const float* b2    = (const float*)d_in[9];
  const float* W2r   = (const float*)d_in[10];
  const float* Wc1   = (const float*)d_in[11];
  const float* bc1   = (const float*)d_in[12];
  const float* Wc2   = (const float*)d_in[13];
  const float* bc2   = (const float*)d_in[14];
  char* ws = (char*)d_ws;
  float* out = (float*)d_out;
  if (ws_size < (size_t)WS_NEED) return;

  int*   flag   = (int*)  (ws + OFF_FLAG);
  float* sc     = (float*)(ws + OFF_SCALE);
  float* sh     = (float*)(ws + OFF_SHIFT);
  int*   gstart = (int*)  (ws + OFF_GSTART);
  int*   bsum   = (int*)  (ws + OFF_BSUM);
  int*   boff   = (int*)  (ws + OFF_BOFF);
  float* psum   = (float*)(ws + OFF_PSUM);
  float* psq    = (float*)(ws + OFF_PSQ);
  float* W1lT   = (float*)(ws + OFF_W1LT);
  float* W1rT   = (float*)(ws + OFF_W1RT);
  float* W2lT   = (float*)(ws + OFF_W2LT);
  float* W2rT   = (float*)(ws + OFF_W2RT);
  float* ro     = (float*)(ws + OFF_RO);
  int*   deg    = (int*)  (ws + OFF_DEG);
  int*   rstart = (int*)  (ws + OFF_RSTART);
  int*   cursor = (int*)  (ws + OFF_CURSOR);
  int*   csr    = (int*)  (ws + OFF_CSR);
  float* h0     = (float*)(ws + OFF_H0);
  float* aggb   = (float*)(ws + OFF_AGG);
  float* h1     = (float*)(ws + OFF_H1);
  int*   src32  = (int*)  (ws + OFF_SRC32);
  int*   dst32  = (int*)  (ws + OFF_DST32);
  float* h2     = h0;   // reuse

  probe_width<<<1, 1, 0, stream>>>((const unsigned*)edge, flag);
  convert_edges<<<(NE+255)/256, 256, 0, stream>>>(edge, flag, src32, dst32);
  transpose_w<<<64, 256, 0, stream>>>(W1l, W1lT);
  transpose_w<<<64, 256, 0, stream>>>(W1r, W1rT);
  transpose_w<<<64, 256, 0, stream>>>(W2l, W2lT);
  transpose_w<<<64, 256, 0, stream>>>(W2r, W2rT);

  hipMemsetAsync(deg, 0, NN*sizeof(int), stream);
  count_deg<<<(NE+255)/256, 256, 0, stream>>>(dst32, deg);
  deg_bsum<<<SCAN_NB, 256, 0, stream>>>(deg, bsum);
  scan_bsum<<<1, 256, 0, stream>>>(bsum, boff);
  scan_apply<<<SCAN_NB, 256, 0, stream>>>(deg, boff, rstart, cursor);
  scatter_edges<<<(NE+255)/256, 256, 0, stream>>>(src32, dst32, cursor, csr);

  bn_stats<<<256, 256, 0, stream>>>(x, psum, psq);
  bn_final<<<1, 128, 0, stream>>>(psum, psq, gamma, beta, sc, sh);
  bn_apply<<<(NN*DIM/4 + 255)/256, 256, 0, stream>>>(x, sc, sh, h0);

  aggregate<<<(NN+3)/4, 256, 0, stream>>>(h0, rstart, csr, aggb);
  sage_linear<<<(NN+63)/64, 256, 0, stream>>>(h0, aggb, W1lT, b1, W1rT, h1);
  aggregate<<<(NN+3)/4, 256, 0, stream>>>(h1, rstart, csr, aggb);
  sage_linear<<<(NN+63)/64, 256, 0, stream>>>(h1, aggb, W2lT, b2, W2rT, h2);

  graph_bounds<<<(NN+1+255)/256, 256, 0, stream>>>(batch, flag, gstart);
  max_pool<<<NGR, 128, 0, stream>>>(h2, gstart, ro);
  classify<<<NGR, 64, 0, stream>>>(ro, Wc1, bc1, Wc2, bc2, out);
}

// Round 2
// 454.584 us; speedup vs baseline: 1.3849x; 1.3849x over previous
//
#include <hip/hip_runtime.h>
#include <math.h>

#define NN 50000
#define NE 800000
#define DIM 128
#define NGR 128
#define SCAN_NB 196   // ceil(NN/256)

typedef short bf16x8 __attribute__((ext_vector_type(8)));
typedef float f32x4  __attribute__((ext_vector_type(4)));

// ---- workspace layout (bytes) ----
#define OFF_FLAG    0
#define OFF_SCALE   1024
#define OFF_SHIFT   2048
#define OFF_GSTART  4096
#define OFF_BSUM    8192
#define OFF_BOFF    16384
#define OFF_PSUM    32768                  // 256*128*4 = 131072
#define OFF_PSQ     (32768+131072)         // ends 294912
#define OFF_WC1     294912                 // 128*256*2 = 65536
#define OFF_WC2     (294912+65536)
#define OFF_RO      (294912+131072)        // 65536
#define OFF_DEG     524288
#define OFF_RSTART  724992
#define OFF_CURSOR  925696
#define OFF_CSR     1126400                // 3.2MB
#define OFF_SRC32   4326400                // 3.2MB
#define OFF_DST32   7526400                // 3.2MB
#define OFF_H0B     12582912               // 12.8MB bf16
#define OFF_H1B     25600000               // 12.8MB bf16
#define OFF_AGGB    38400000               // 12.8MB bf16
#define WS_NEED     51200000

__device__ __forceinline__ unsigned short f2b(float f) {
  union { float f; unsigned u; } v; v.f = f;
  unsigned r = (v.u + 0x7FFF + ((v.u >> 16) & 1)) >> 16;   // RNE
  return (unsigned short)r;
}
__device__ __forceinline__ float b2f(unsigned short h) {
  union { unsigned u; float f; } v; v.u = ((unsigned)h) << 16;
  return v.f;
}

// detect int64 vs int32 index buffers
__global__ void probe_width(const unsigned* __restrict__ e, int* flag) {
  unsigned acc = 0;
  for (int i = 0; i < 64; ++i) acc |= e[2*i+1];
  *flag = (acc == 0) ? 1 : 0;
}

__global__ void convert_edges(const void* __restrict__ edge, const int* __restrict__ flag,
                              int* __restrict__ src, int* __restrict__ dst) {
  int e = blockIdx.x*blockDim.x + threadIdx.x;
  if (e >= NE) return;
  if (*flag) {
    const long long* p = (const long long*)edge;
    src[e] = (int)p[e];
    dst[e] = (int)p[NE + e];
  } else {
    const int* p = (const int*)edge;
    src[e] = p[e];
    dst[e] = p[NE + e];
  }
}

// pack [Wl | Wr] row-major -> bf16 Wcat[j][0:256]
__global__ void pack_weights(const float* __restrict__ Wl, const float* __restrict__ Wr,
                             unsigned short* __restrict__ Wcat) {
  int i = blockIdx.x*blockDim.x + threadIdx.x;   // 32768
  int j = i >> 8, k = i & 255;
  float v = (k < 128) ? Wl[j*128 + k] : Wr[j*128 + (k-128)];
  Wcat[i] = f2b(v);
}

__global__ void bn_stats(const float* __restrict__ x, float* __restrict__ psum,
                         float* __restrict__ psq) {
  int col  = threadIdx.x & 127;
  int half = threadIdx.x >> 7;
  float s = 0.f, q = 0.f;
  for (int r = blockIdx.x*2 + half; r < NN; r += 512) {
    float v = x[(size_t)r*DIM + col];
    s += v; q += v*v;
  }
  __shared__ float ss[128], sq[128];
  if (half) { ss[col] = s; sq[col] = q; }
  __syncthreads();
  if (!half) {
    psum[blockIdx.x*DIM + col] = s + ss[col];
    psq [blockIdx.x*DIM + col] = q + sq[col];
  }
}

__global__ void bn_final(const float* __restrict__ psum, const float* __restrict__ psq,
                         const float* __restrict__ gamma, const float* __restrict__ beta,
                         float* __restrict__ sc, float* __restrict__ sh) {
  int c = threadIdx.x;
  float s = 0.f, q = 0.f;
  for (int b = 0; b < 256; ++b) { s += psum[b*DIM+c]; q += psq[b*DIM+c]; }
  float mu  = s * (1.0f/NN);
  float var = q * (1.0f/NN) - mu*mu;     // biased variance
  float a = gamma[c] * rsqrtf(var + 1e-5f);
  sc[c] = a;
  sh[c] = beta[c] - mu*a;
}

// x fp32 -> h0 bf16 (normalized)
__global__ void bn_apply(const float* __restrict__ x, const float* __restrict__ sc,
                         const float* __restrict__ sh, unsigned short* __restrict__ h0) {
  long i = (long)blockIdx.x*256 + threadIdx.x;
  if (i >= (long)NN*DIM/4) return;
  int c4 = (int)((i*4) & (DIM-1));
  float4 v = ((const float4*)x)[i];
  ushort4 r;
  r.x = f2b(v.x*sc[c4+0] + sh[c4+0]);
  r.y = f2b(v.y*sc[c4+1] + sh[c4+1]);
  r.z = f2b(v.z*sc[c4+2] + sh[c4+2]);
  r.w = f2b(v.w*sc[c4+3] + sh[c4+3]);
  ((ushort4*)h0)[i] = r;
}

__global__ void count_deg(const int* __restrict__ dst, int* __restrict__ deg) {
  int e = blockIdx.x*blockDim.x + threadIdx.x;
  if (e < NE) atomicAdd(&deg[dst[e]], 1);
}

__global__ void deg_bsum(const int* __restrict__ deg, int* __restrict__ bsum) {
  __shared__ int sm[256];
  int i = blockIdx.x*256 + threadIdx.x;
  sm[threadIdx.x] = (i < NN) ? deg[i] : 0;
  __syncthreads();
  for (int off = 128; off > 0; off >>= 1) {
    if (threadIdx.x < off) sm[threadIdx.x] += sm[threadIdx.x + off];
    __syncthreads();
  }
  if (threadIdx.x == 0) bsum[blockIdx.x] = sm[0];
}

__global__ void scan_bsum(const int* __restrict__ bsum, int* __restrict__ boff) {
  __shared__ int sm[256];
  int t = threadIdx.x;
  int v = (t < SCAN_NB) ? bsum[t] : 0;
  sm[t] = v;
  __syncthreads();
  for (int off = 1; off < 256; off <<= 1) {
    int xx = (t >= off) ? sm[t-off] : 0;
    __syncthreads();
    sm[t] += xx;
    __syncthreads();
  }
  if (t < SCAN_NB) boff[t] = sm[t] - v;   // exclusive
}

__global__ void scan_apply(const int* __restrict__ deg, const int* __restrict__ boff,
                           int* __restrict__ row_start, int* __restrict__ cursor) {
  __shared__ int sm[256];
  int t = threadIdx.x;
  int i = blockIdx.x*256 + t;
  int v = (i < NN) ? deg[i] : 0;
  sm[t] = v;
  __syncthreads();
  for (int off = 1; off < 256; off <<= 1) {
    int xx = (t >= off) ? sm[t-off] : 0;
    __syncthreads();
    sm[t] += xx;
    __syncthreads();
  }
  int ex = boff[blockIdx.x] + sm[t] - v;
  if (i < NN) { row_start[i] = ex; cursor[i] = ex; }
  if (i == NN-1) row_start[NN] = ex + v;  // == NE
}

__global__ void scatter_edges(const int* __restrict__ src, const int* __restrict__ dst,
                              int* __restrict__ cursor, int* __restrict__ csr_src) {
  int e = blockIdx.x*blockDim.x + threadIdx.x;
  if (e >= NE) return;
  int d = dst[e];
  int pos = atomicAdd(&cursor[d], 1);
  csr_src[pos] = src[e];
}

// one wave per node; lane covers 2 bf16 (uint) of the 128-dim row
__global__ void aggregate(const unsigned* __restrict__ h, const int* __restrict__ row_start,
                          const int* __restrict__ csr_src, unsigned* __restrict__ out) {
  int node = blockIdx.x*4 + (threadIdx.x >> 6);
  if (node >= NN) return;
  int lane = threadIdx.x & 63;
  int p0 = row_start[node], p1 = row_start[node+1];
  float ax = 0.f, ay = 0.f;
  for (int p = p0; p < p1; ++p) {
    int s = csr_src[p];
    unsigned v = h[(size_t)s*64 + lane];
    ax += b2f((unsigned short)(v & 0xffff));
    ay += b2f((unsigned short)(v >> 16));
  }
  int d = p1 - p0;
  float inv = 1.0f / (float)(d > 1 ? d : 1);
  unsigned lo = f2b(ax*inv), hi = f2b(ay*inv);
  out[(size_t)node*64 + lane] = (hi << 16) | lo;
}

// fused SAGE layer: hout = ELU( [agg|root](bf16) @ Wcat^T(bf16) + bias ), MFMA fp32-accum
// block=256 (4 waves), wave w owns rows [blk*64 + w*16, +16), all 128 cols.
// A frag: lane holds row (l&15), k = kc*32 + 8*(l>>4)+e (16B global load)
// B frag: from row-major Wcat[j][256]: lane holds col j=jf*16+(l&15), same k chunk.
// D frag: col = l&15, row = 4*(l>>4)+r.
__global__ __launch_bounds__(256) void sage_mfma(
    const unsigned short* __restrict__ aggb, const unsigned short* __restrict__ rootb,
    const unsigned short* __restrict__ Wcat, const float* __restrict__ bias,
    unsigned short* __restrict__ hout) {
  int t = threadIdx.x;
  int lane = t & 63;
  int w = t >> 6;
  int m0 = blockIdx.x*64 + w*16;
  int l15 = lane & 15, lg = lane >> 4;

  int rowA = m0 + l15; if (rowA > NN-1) rowA = NN-1;
  f32x4 acc[8];
  #pragma unroll
  for (int jf = 0; jf < 8; ++jf) acc[jf] = (f32x4){0.f,0.f,0.f,0.f};

  #pragma unroll
  for (int kc = 0; kc < 8; ++kc) {
    const unsigned short* ab = (kc < 4) ? aggb : rootb;
    bf16x8 a = *(const bf16x8*)(ab + (size_t)rowA*128 + (kc & 3)*32 + 8*lg);
    #pragma unroll
    for (int jf = 0; jf < 8; ++jf) {
      bf16x8 b = *(const bf16x8*)(Wcat + (size_t)(jf*16 + l15)*256 + kc*32 + 8*lg);
      acc[jf] = __builtin_amdgcn_mfma_f32_16x16x32_bf16(a, b, acc[jf], 0, 0, 0);
    }
  }

  #pragma unroll
  for (int jf = 0; jf < 8; ++jf) {
    int col = jf*16 + l15;
    float bj = bias[col];
    #pragma unroll
    for (int r = 0; r < 4; ++r) {
      int node = m0 + 4*lg + r;
      float v = acc[jf][r] + bj;
      v = (v > 0.f) ? v : (expf(v) - 1.0f);    // ELU
      if (node < NN) hout[(size_t)node*128 + col] = f2b(v);
    }
  }
}

__global__ void graph_bounds(const void* __restrict__ batch, const int* __restrict__ flag,
                             int* __restrict__ gstart) {
  int n = blockIdx.x*blockDim.x + threadIdx.x;
  if (n > NN) return;
  bool w = (*flag != 0);
  int bn = NGR, bp = -1;
  if (n < NN) bn = w ? (int)((const long long*)batch)[n]   : ((const int*)batch)[n];
  if (n > 0)  bp = w ? (int)((const long long*)batch)[n-1] : ((const int*)batch)[n-1];
  for (int g = bp + 1; g <= bn; ++g) gstart[g] = n;   // gstart[g] = lower_bound(batch, g)
}

__global__ void max_pool(const unsigned short* __restrict__ h, const int* __restrict__ gstart,
                         float* __restrict__ ro) {
  int g = blockIdx.x, c = threadIdx.x;
  int s = gstart[g], e = gstart[g+1];
  float m = -INFINITY;
  for (int n = s; n < e; ++n) m = fmaxf(m, b2f(h[(size_t)n*DIM + c]));
  ro[g*DIM + c] = m;
}

__global__ void classify(const float* __restrict__ ro,
                         const float* __restrict__ Wc1, const float* __restrict__ bc1,
                         const float* __restrict__ Wc2, const float* __restrict__ bc2,
                         float* __restrict__ out) {
  int g = blockIdx.x, t = threadIdx.x;   // 64 threads
  __shared__ float row[128];
  __shared__ float rv[64];
  row[t]      = ro[g*DIM + t];
  row[t + 64] = ro[g*DIM + 64 + t];
  __syncthreads();
  float acc = bc1[t];
  for (int k = 0; k < 128; ++k) acc += row[k] * Wc1[t*128 + k];
  rv[t] = acc;
  out[1280 + g*64 + t] = acc;            // rv output (second tuple element)
  __syncthreads();
  if (t < 10) {
    float o = bc2[t];
    for (int k = 0; k < 64; ++k) o += rv[k] * Wc2[t*64 + k];
    out[g*10 + t] = o;                   // logits (first tuple element)
  }
}

extern "C" void kernel_launch(void* const* d_in, const int* in_sizes, int n_in,
                              void* d_out, int out_size, void* d_ws, size_t ws_size,
                              hipStream_t stream) {
  const float* x     = (const float*)d_in[0];
  const void*  edge  = d_in[1];
  const void*  batch = d_in[2];
  const float* gamma = (const float*)d_in[3];
  const float* beta  = (const float*)d_in[4];
  const float* W1l   = (const float*)d_in[5];
  const float* b1    = (const float*)d_in[6];
  const float* W1r   = (const float*)d_in[7];
  const float* W2l   = (const float*)d_in[8];
  const float* b2    = (const float*)d_in[9];
  const float* W2r   = (const float*)d_in[10];
  const float* Wc1   = (const float*)d_in[11];
  const float* bc1   = (const float*)d_in[12];
  const float* Wc2   = (const float*)d_in[13];
  const float* bc2   = (const float*)d_in[14];
  char* ws = (char*)d_ws;
  float* out = (float*)d_out;
  if (ws_size < (size_t)WS_NEED) return;

  int*   flag   = (int*)  (ws + OFF_FLAG);
  float* sc     = (float*)(ws + OFF_SCALE);
  float* sh     = (float*)(ws + OFF_SHIFT);
  int*   gstart = (int*)  (ws + OFF_GSTART);
  int*   bsum   = (int*)  (ws + OFF_BSUM);
  int*   boff   = (int*)  (ws + OFF_BOFF);
  float* psum   = (float*)(ws + OFF_PSUM);
  float* psq    = (float*)(ws + OFF_PSQ);
  unsigned short* Wcat1 = (unsigned short*)(ws + OFF_WC1);
  unsigned short* Wcat2 = (unsigned short*)(ws + OFF_WC2);
  float* ro     = (float*)(ws + OFF_RO);
  int*   deg    = (int*)  (ws + OFF_DEG);
  int*   rstart = (int*)  (ws + OFF_RSTART);
  int*   cursor = (int*)  (ws + OFF_CURSOR);
  int*   csr    = (int*)  (ws + OFF_CSR);
  int*   src32  = (int*)  (ws + OFF_SRC32);
  int*   dst32  = (int*)  (ws + OFF_DST32);
  unsigned short* h0b  = (unsigned short*)(ws + OFF_H0B);
  unsigned short* h1b  = (unsigned short*)(ws + OFF_H1B);
  unsigned short* aggb = (unsigned short*)(ws + OFF_AGGB);
  unsigned short* h2b  = h0b;   // reuse

  probe_width<<<1, 1, 0, stream>>>((const unsigned*)edge, flag);
  convert_edges<<<(NE+255)/256, 256, 0, stream>>>(edge, flag, src32, dst32);
  pack_weights<<<128, 256, 0, stream>>>(W1l, W1r, Wcat1);
  pack_weights<<<128, 256, 0, stream>>>(W2l, W2r, Wcat2);

  hipMemsetAsync(deg, 0, NN*sizeof(int), stream);
  count_deg<<<(NE+255)/256, 256, 0, stream>>>(dst32, deg);
  deg_bsum<<<SCAN_NB, 256, 0, stream>>>(deg, bsum);
  scan_bsum<<<1, 256, 0, stream>>>(bsum, boff);
  scan_apply<<<SCAN_NB, 256, 0, stream>>>(deg, boff, rstart, cursor);
  scatter_edges<<<(NE+255)/256, 256, 0, stream>>>(src32, dst32, cursor, csr);

  bn_stats<<<256, 256, 0, stream>>>(x, psum, psq);
  bn_final<<<1, 128, 0, stream>>>(psum, psq, gamma, beta, sc, sh);
  bn_apply<<<(NN*DIM/4 + 255)/256, 256, 0, stream>>>(x, sc, sh, h0b);

  aggregate<<<(NN+3)/4, 256, 0, stream>>>((const unsigned*)h0b, rstart, csr, (unsigned*)aggb);
  sage_mfma<<<(NN+63)/64, 256, 0, stream>>>(aggb, h0b, Wcat1, b1, h1b);
  aggregate<<<(NN+3)/4, 256, 0, stream>>>((const unsigned*)h1b, rstart, csr, (unsigned*)aggb);
  sage_mfma<<<(NN+63)/64, 256, 0, stream>>>(aggb, h1b, Wcat2, b2, h2b);

  graph_bounds<<<(NN+1+255)/256, 256, 0, stream>>>(batch, flag, gstart);
  max_pool<<<NGR, 128, 0, stream>>>(h2b, gstart, ro);
  classify<<<NGR, 64, 0, stream>>>(ro, Wc1, bc1, Wc2, bc2, out);
}

// Round 3
// 366.565 us; speedup vs baseline: 1.7175x; 1.2401x over previous
//
#include <hip/hip_runtime.h>
#include <math.h>

#define NN 50000
#define NE 800000
#define DIM 128
#define NGR 128
#define SCAN_NB 196   // ceil(NN/256)

typedef short bf16x8 __attribute__((ext_vector_type(8)));
typedef float f32x4  __attribute__((ext_vector_type(4)));

// ---- workspace layout (bytes) ----
#define OFF_FLAG    0
#define OFF_SCALE   1024
#define OFF_SHIFT   2048
#define OFF_GSTART  4096
#define OFF_BSUM    8192
#define OFF_BOFF    16384
#define OFF_PSUM    32768                  // 256*128*4 = 131072
#define OFF_PSQ     (32768+131072)         // ends 294912
#define OFF_WC1     294912                 // 128*256*2 = 65536
#define OFF_WC2     (294912+65536)
#define OFF_RO      (294912+131072)        // 65536
#define OFF_DEG     524288
#define OFF_RSTART  724992
#define OFF_CURSOR  925696
#define OFF_CSR     1126400                // 3.2MB
#define OFF_H0B     12582912               // 12.8MB bf16
#define OFF_H1B     25600000               // 12.8MB bf16
#define OFF_AGGB    38400000               // 12.8MB bf16
#define WS_NEED     51200000

__device__ __forceinline__ unsigned short f2b(float f) {
  union { float f; unsigned u; } v; v.f = f;
  unsigned r = (v.u + 0x7FFF + ((v.u >> 16) & 1)) >> 16;   // RNE
  return (unsigned short)r;
}
__device__ __forceinline__ float b2f(unsigned short h) {
  union { unsigned u; float f; } v; v.u = ((unsigned)h) << 16;
  return v.f;
}

// detect int64 vs int32 index buffers
__global__ void probe_width(const unsigned* __restrict__ e, int* flag) {
  unsigned acc = 0;
  for (int i = 0; i < 64; ++i) acc |= e[2*i+1];
  *flag = (acc == 0) ? 1 : 0;
}

// pack [Wl | Wr] row-major -> bf16 Wcat[j][0:256]
__global__ void pack_weights(const float* __restrict__ Wl, const float* __restrict__ Wr,
                             unsigned short* __restrict__ Wcat) {
  int i = blockIdx.x*blockDim.x + threadIdx.x;   // 32768
  int j = i >> 8, k = i & 255;
  float v = (k < 128) ? Wl[j*128 + k] : Wr[j*128 + (k-128)];
  Wcat[i] = f2b(v);
}

__global__ void bn_stats(const float* __restrict__ x, float* __restrict__ psum,
                         float* __restrict__ psq) {
  int col  = threadIdx.x & 127;
  int half = threadIdx.x >> 7;
  float s = 0.f, q = 0.f;
  for (int r = blockIdx.x*2 + half; r < NN; r += 512) {
    float v = x[(size_t)r*DIM + col];
    s += v; q += v*v;
  }
  __shared__ float ss[128], sq[128];
  if (half) { ss[col] = s; sq[col] = q; }
  __syncthreads();
  if (!half) {
    psum[blockIdx.x*DIM + col] = s + ss[col];
    psq [blockIdx.x*DIM + col] = q + sq[col];
  }
}

__global__ void bn_final(const float* __restrict__ psum, const float* __restrict__ psq,
                         const float* __restrict__ gamma, const float* __restrict__ beta,
                         float* __restrict__ sc, float* __restrict__ sh) {
  int c = threadIdx.x;
  float s = 0.f, q = 0.f;
  for (int b = 0; b < 256; ++b) { s += psum[b*DIM+c]; q += psq[b*DIM+c]; }
  float mu  = s * (1.0f/NN);
  float var = q * (1.0f/NN) - mu*mu;     // biased variance
  float a = gamma[c] * rsqrtf(var + 1e-5f);
  sc[c] = a;
  sh[c] = beta[c] - mu*a;
}

// x fp32 -> h0 bf16 (normalized)
__global__ void bn_apply(const float* __restrict__ x, const float* __restrict__ sc,
                         const float* __restrict__ sh, unsigned short* __restrict__ h0) {
  long i = (long)blockIdx.x*256 + threadIdx.x;
  if (i >= (long)NN*DIM/4) return;
  int c4 = (int)((i*4) & (DIM-1));
  float4 v = ((const float4*)x)[i];
  ushort4 r;
  r.x = f2b(v.x*sc[c4+0] + sh[c4+0]);
  r.y = f2b(v.y*sc[c4+1] + sh[c4+1]);
  r.z = f2b(v.z*sc[c4+2] + sh[c4+2]);
  r.w = f2b(v.w*sc[c4+3] + sh[c4+3]);
  ((ushort4*)h0)[i] = r;
}

__global__ void count_deg(const void* __restrict__ edge, const int* __restrict__ flag,
                          int* __restrict__ deg) {
  int e = blockIdx.x*blockDim.x + threadIdx.x;
  if (e >= NE) return;
  int d = (*flag) ? (int)((const long long*)edge)[NE + e] : ((const int*)edge)[NE + e];
  atomicAdd(&deg[d], 1);
}

__global__ void deg_bsum(const int* __restrict__ deg, int* __restrict__ bsum) {
  __shared__ int sm[256];
  int i = blockIdx.x*256 + threadIdx.x;
  sm[threadIdx.x] = (i < NN) ? deg[i] : 0;
  __syncthreads();
  for (int off = 128; off > 0; off >>= 1) {
    if (threadIdx.x < off) sm[threadIdx.x] += sm[threadIdx.x + off];
    __syncthreads();
  }
  if (threadIdx.x == 0) bsum[blockIdx.x] = sm[0];
}

__global__ void scan_bsum(const int* __restrict__ bsum, int* __restrict__ boff) {
  __shared__ int sm[256];
  int t = threadIdx.x;
  int v = (t < SCAN_NB) ? bsum[t] : 0;
  sm[t] = v;
  __syncthreads();
  for (int off = 1; off < 256; off <<= 1) {
    int xx = (t >= off) ? sm[t-off] : 0;
    __syncthreads();
    sm[t] += xx;
    __syncthreads();
  }
  if (t < SCAN_NB) boff[t] = sm[t] - v;   // exclusive
}

__global__ void scan_apply(const int* __restrict__ deg, const int* __restrict__ boff,
                           int* __restrict__ row_start, int* __restrict__ cursor) {
  __shared__ int sm[256];
  int t = threadIdx.x;
  int i = blockIdx.x*256 + t;
  int v = (i < NN) ? deg[i] : 0;
  sm[t] = v;
  __syncthreads();
  for (int off = 1; off < 256; off <<= 1) {
    int xx = (t >= off) ? sm[t-off] : 0;
    __syncthreads();
    sm[t] += xx;
    __syncthreads();
  }
  int ex = boff[blockIdx.x] + sm[t] - v;
  if (i < NN) { row_start[i] = ex; cursor[i] = ex; }
  if (i == NN-1) row_start[NN] = ex + v;  // == NE
}

__global__ void scatter_edges(const void* __restrict__ edge, const int* __restrict__ flag,
                              int* __restrict__ cursor, int* __restrict__ csr_src) {
  int e = blockIdx.x*blockDim.x + threadIdx.x;
  if (e >= NE) return;
  int s, d;
  if (*flag) {
    s = (int)((const long long*)edge)[e];
    d = (int)((const long long*)edge)[NE + e];
  } else {
    s = ((const int*)edge)[e];
    d = ((const int*)edge)[NE + e];
  }
  int pos = atomicAdd(&cursor[d], 1);
  csr_src[pos] = s;
}

// one wave per node; 4 lane-groups of 16 each own a different neighbor
// (16B dwordx4 per lane covers the 256B row), index load pipelined one
// iteration ahead; cross-group combine via shfl_xor(16/32).
__global__ __launch_bounds__(256) void aggregate(
    const unsigned short* __restrict__ h, const int* __restrict__ row_start,
    const int* __restrict__ csr_src, unsigned short* __restrict__ out) {
  int node = blockIdx.x*4 + (threadIdx.x >> 6);
  if (node >= NN) return;
  int lane = threadIdx.x & 63;
  int grp = lane >> 4, l15 = lane & 15;
  int p0 = row_start[node], p1 = row_start[node+1];

  float acc[8];
  #pragma unroll
  for (int j = 0; j < 8; ++j) acc[j] = 0.f;

  int p = p0 + grp;
  int s = (p < p1) ? csr_src[p] : -1;
  while (s >= 0) {
    int pn = p + 4;
    int sn = (pn < p1) ? csr_src[pn] : -1;
    uint4 v = *(const uint4*)(h + (size_t)s*128 + l15*8);
    acc[0] += __uint_as_float(v.x << 16);
    acc[1] += __uint_as_float(v.x & 0xffff0000u);
    acc[2] += __uint_as_float(v.y << 16);
    acc[3] += __uint_as_float(v.y & 0xffff0000u);
    acc[4] += __uint_as_float(v.z << 16);
    acc[5] += __uint_as_float(v.z & 0xffff0000u);
    acc[6] += __uint_as_float(v.w << 16);
    acc[7] += __uint_as_float(v.w & 0xffff0000u);
    p = pn; s = sn;
  }

  #pragma unroll
  for (int j = 0; j < 8; ++j) {
    acc[j] += __shfl_xor(acc[j], 16);
    acc[j] += __shfl_xor(acc[j], 32);
  }

  int d = p1 - p0;
  float inv = 1.0f / (float)(d > 1 ? d : 1);
  if (lane < 16) {
    uint4 o;
    o.x = ((unsigned)f2b(acc[1]*inv) << 16) | f2b(acc[0]*inv);
    o.y = ((unsigned)f2b(acc[3]*inv) << 16) | f2b(acc[2]*inv);
    o.z = ((unsigned)f2b(acc[5]*inv) << 16) | f2b(acc[4]*inv);
    o.w = ((unsigned)f2b(acc[7]*inv) << 16) | f2b(acc[6]*inv);
    *(uint4*)(out + (size_t)node*128 + l15*8) = o;
  }
}

// fused SAGE layer: hout = ELU( [agg|root](bf16) @ Wcat^T(bf16) + bias ), MFMA fp32-accum
__global__ __launch_bounds__(256) void sage_mfma(
    const unsigned short* __restrict__ aggb, const unsigned short* __restrict__ rootb,
    const unsigned short* __restrict__ Wcat, const float* __restrict__ bias,
    unsigned short* __restrict__ hout) {
  int t = threadIdx.x;
  int lane = t & 63;
  int w = t >> 6;
  int m0 = blockIdx.x*64 + w*16;
  int l15 = lane & 15, lg = lane >> 4;

  int rowA = m0 + l15; if (rowA > NN-1) rowA = NN-1;
  f32x4 acc[8];
  #pragma unroll
  for (int jf = 0; jf < 8; ++jf) acc[jf] = (f32x4){0.f,0.f,0.f,0.f};

  #pragma unroll
  for (int kc = 0; kc < 8; ++kc) {
    const unsigned short* ab = (kc < 4) ? aggb : rootb;
    bf16x8 a = *(const bf16x8*)(ab + (size_t)rowA*128 + (kc & 3)*32 + 8*lg);
    #pragma unroll
    for (int jf = 0; jf < 8; ++jf) {
      bf16x8 b = *(const bf16x8*)(Wcat + (size_t)(jf*16 + l15)*256 + kc*32 + 8*lg);
      acc[jf] = __builtin_amdgcn_mfma_f32_16x16x32_bf16(a, b, acc[jf], 0, 0, 0);
    }
  }

  #pragma unroll
  for (int jf = 0; jf < 8; ++jf) {
    int col = jf*16 + l15;
    float bj = bias[col];
    #pragma unroll
    for (int r = 0; r < 4; ++r) {
      int node = m0 + 4*lg + r;
      float v = acc[jf][r] + bj;
      v = (v > 0.f) ? v : (expf(v) - 1.0f);    // ELU
      if (node < NN) hout[(size_t)node*128 + col] = f2b(v);
    }
  }
}

__global__ void graph_bounds(const void* __restrict__ batch, const int* __restrict__ flag,
                             int* __restrict__ gstart) {
  int n = blockIdx.x*blockDim.x + threadIdx.x;
  if (n > NN) return;
  bool w = (*flag != 0);
  int bn = NGR, bp = -1;
  if (n < NN) bn = w ? (int)((const long long*)batch)[n]   : ((const int*)batch)[n];
  if (n > 0)  bp = w ? (int)((const long long*)batch)[n-1] : ((const int*)batch)[n-1];
  for (int g = bp + 1; g <= bn; ++g) gstart[g] = n;   // gstart[g] = lower_bound(batch, g)
}

__global__ void max_pool(const unsigned short* __restrict__ h, const int* __restrict__ gstart,
                         float* __restrict__ ro) {
  int g = blockIdx.x, c = threadIdx.x;
  int s = gstart[g], e = gstart[g+1];
  float m = -INFINITY;
  for (int n = s; n < e; ++n) m = fmaxf(m, b2f(h[(size_t)n*DIM + c]));
  ro[g*DIM + c] = m;
}

__global__ void classify(const float* __restrict__ ro,
                         const float* __restrict__ Wc1, const float* __restrict__ bc1,
                         const float* __restrict__ Wc2, const float* __restrict__ bc2,
                         float* __restrict__ out) {
  int g = blockIdx.x, t = threadIdx.x;   // 64 threads
  __shared__ float row[128];
  __shared__ float rv[64];
  row[t]      = ro[g*DIM + t];
  row[t + 64] = ro[g*DIM + 64 + t];
  __syncthreads();
  float acc = bc1[t];
  for (int k = 0; k < 128; ++k) acc += row[k] * Wc1[t*128 + k];
  rv[t] = acc;
  out[1280 + g*64 + t] = acc;            // rv output (second tuple element)
  __syncthreads();
  if (t < 10) {
    float o = bc2[t];
    for (int k = 0; k < 64; ++k) o += rv[k] * Wc2[t*64 + k];
    out[g*10 + t] = o;                   // logits (first tuple element)
  }
}

extern "C" void kernel_launch(void* const* d_in, const int* in_sizes, int n_in,
                              void* d_out, int out_size, void* d_ws, size_t ws_size,
                              hipStream_t stream) {
  const float* x     = (const float*)d_in[0];
  const void*  edge  = d_in[1];
  const void*  batch = d_in[2];
  const float* gamma = (const float*)d_in[3];
  const float* beta  = (const float*)d_in[4];
  const float* W1l   = (const float*)d_in[5];
  const float* b1    = (const float*)d_in[6];
  const float* W1r   = (const float*)d_in[7];
  const float* W2l   = (const float*)d_in[8];
  const float* b2    = (const float*)d_in[9];
  const float* W2r   = (const float*)d_in[10];
  const float* Wc1   = (const float*)d_in[11];
  const float* bc1   = (const float*)d_in[12];
  const float* Wc2   = (const float*)d_in[13];
  const float* bc2   = (const float*)d_in[14];
  char* ws = (char*)d_ws;
  float* out = (float*)d_out;
  if (ws_size < (size_t)WS_NEED) return;

  int*   flag   = (int*)  (ws + OFF_FLAG);
  float* sc     = (float*)(ws + OFF_SCALE);
  float* sh     = (float*)(ws + OFF_SHIFT);
  int*   gstart = (int*)  (ws + OFF_GSTART);
  int*   bsum   = (int*)  (ws + OFF_BSUM);
  int*   boff   = (int*)  (ws + OFF_BOFF);
  float* psum   = (float*)(ws + OFF_PSUM);
  float* psq    = (float*)(ws + OFF_PSQ);
  unsigned short* Wcat1 = (unsigned short*)(ws + OFF_WC1);
  unsigned short* Wcat2 = (unsigned short*)(ws + OFF_WC2);
  float* ro     = (float*)(ws + OFF_RO);
  int*   deg    = (int*)  (ws + OFF_DEG);
  int*   rstart = (int*)  (ws + OFF_RSTART);
  int*   cursor = (int*)  (ws + OFF_CURSOR);
  int*   csr    = (int*)  (ws + OFF_CSR);
  unsigned short* h0b  = (unsigned short*)(ws + OFF_H0B);
  unsigned short* h1b  = (unsigned short*)(ws + OFF_H1B);
  unsigned short* aggb = (unsigned short*)(ws + OFF_AGGB);
  unsigned short* h2b  = h0b;   // reuse

  probe_width<<<1, 1, 0, stream>>>((const unsigned*)edge, flag);
  pack_weights<<<128, 256, 0, stream>>>(W1l, W1r, Wcat1);
  pack_weights<<<128, 256, 0, stream>>>(W2l, W2r, Wcat2);

  hipMemsetAsync(deg, 0, NN*sizeof(int), stream);
  count_deg<<<(NE+255)/256, 256, 0, stream>>>(edge, flag, deg);
  deg_bsum<<<SCAN_NB, 256, 0, stream>>>(deg, bsum);
  scan_bsum<<<1, 256, 0, stream>>>(bsum, boff);
  scan_apply<<<SCAN_NB, 256, 0, stream>>>(deg, boff, rstart, cursor);
  scatter_edges<<<(NE+255)/256, 256, 0, stream>>>(edge, flag, cursor, csr);

  bn_stats<<<256, 256, 0, stream>>>(x, psum, psq);
  bn_final<<<1, 128, 0, stream>>>(psum, psq, gamma, beta, sc, sh);
  bn_apply<<<(NN*DIM/4 + 255)/256, 256, 0, stream>>>(x, sc, sh, h0b);

  aggregate<<<(NN+3)/4, 256, 0, stream>>>(h0b, rstart, csr, aggb);
  sage_mfma<<<(NN+63)/64, 256, 0, stream>>>(aggb, h0b, Wcat1, b1, h1b);
  aggregate<<<(NN+3)/4, 256, 0, stream>>>(h1b, rstart, csr, aggb);
  sage_mfma<<<(NN+63)/64, 256, 0, stream>>>(aggb, h1b, Wcat2, b2, h2b);

  graph_bounds<<<(NN+1+255)/256, 256, 0, stream>>>(batch, flag, gstart);
  max_pool<<<NGR, 128, 0, stream>>>(h2b, gstart, ro);
  classify<<<NGR, 64, 0, stream>>>(ro, Wc1, bc1, Wc2, bc2, out);
}

// Round 4
// 301.356 us; speedup vs baseline: 2.0891x; 1.2164x over previous
//
#include <hip/hip_runtime.h>
#include <math.h>

#define NN 50000
#define NE 800000
#define DIM 128
#define NGR 128
#define SCAN_NB 196   // ceil(NN/256)
#define MP_SLICES 16

typedef short bf16x8 __attribute__((ext_vector_type(8)));
typedef float f32x4  __attribute__((ext_vector_type(4)));

// ---- workspace layout (bytes) ----
#define OFF_FLAG    0
#define OFF_SCALE   1024
#define OFF_SHIFT   2048
#define OFF_GSTART  4096
#define OFF_BSUM    8192
#define OFF_BOFF    16384
#define OFF_PSUM    32768                  // 256*128*4 = 131072
#define OFF_PSQ     (32768+131072)         // ends 294912
#define OFF_WC1     294912                 // 128*256*2 = 65536
#define OFF_WC2     (294912+65536)
#define OFF_RO      (294912+131072)        // 65536
#define OFF_DEG     524288
#define OFF_RSTART  724992
#define OFF_CURSOR  925696
#define OFF_CSR     1126400                // 3.2MB
#define OFF_PART    4326400                // 1MB (maxpool partials)
#define OFF_H0B     12582912               // 12.8MB bf16
#define OFF_H1B     25600000               // 12.8MB bf16
#define OFF_AGGB    38400000               // 12.8MB bf16
#define WS_NEED     51200000

__device__ __forceinline__ unsigned short f2b(float f) {
  union { float f; unsigned u; } v; v.f = f;
  unsigned r = (v.u + 0x7FFF + ((v.u >> 16) & 1)) >> 16;   // RNE
  return (unsigned short)r;
}
__device__ __forceinline__ float b2f(unsigned short h) {
  union { unsigned u; float f; } v; v.u = ((unsigned)h) << 16;
  return v.f;
}

// detect int64 vs int32 index buffers
__global__ void probe_width(const unsigned* __restrict__ e, int* flag) {
  unsigned acc = 0;
  for (int i = 0; i < 64; ++i) acc |= e[2*i+1];
  *flag = (acc == 0) ? 1 : 0;
}

// pack [Wl | Wr] row-major -> bf16 Wcat[j][0:256]
__global__ void pack_weights(const float* __restrict__ Wl, const float* __restrict__ Wr,
                             unsigned short* __restrict__ Wcat) {
  int i = blockIdx.x*blockDim.x + threadIdx.x;   // 32768
  int j = i >> 8, k = i & 255;
  float v = (k < 128) ? Wl[j*128 + k] : Wr[j*128 + (k-128)];
  Wcat[i] = f2b(v);
}

__global__ void bn_stats(const float* __restrict__ x, float* __restrict__ psum,
                         float* __restrict__ psq) {
  int col  = threadIdx.x & 127;
  int half = threadIdx.x >> 7;
  float s = 0.f, q = 0.f;
  for (int r = blockIdx.x*2 + half; r < NN; r += 512) {
    float v = x[(size_t)r*DIM + col];
    s += v; q += v*v;
  }
  __shared__ float ss[128], sq[128];
  if (half) { ss[col] = s; sq[col] = q; }
  __syncthreads();
  if (!half) {
    psum[blockIdx.x*DIM + col] = s + ss[col];
    psq [blockIdx.x*DIM + col] = q + sq[col];
  }
}

__global__ void bn_final(const float* __restrict__ psum, const float* __restrict__ psq,
                         const float* __restrict__ gamma, const float* __restrict__ beta,
                         float* __restrict__ sc, float* __restrict__ sh) {
  int c = threadIdx.x;
  float s = 0.f, q = 0.f;
  for (int b = 0; b < 256; ++b) { s += psum[b*DIM+c]; q += psq[b*DIM+c]; }
  float mu  = s * (1.0f/NN);
  float var = q * (1.0f/NN) - mu*mu;     // biased variance
  float a = gamma[c] * rsqrtf(var + 1e-5f);
  sc[c] = a;
  sh[c] = beta[c] - mu*a;
}

// x fp32 -> h0 bf16 (normalized)
__global__ void bn_apply(const float* __restrict__ x, const float* __restrict__ sc,
                         const float* __restrict__ sh, unsigned short* __restrict__ h0) {
  long i = (long)blockIdx.x*256 + threadIdx.x;
  if (i >= (long)NN*DIM/4) return;
  int c4 = (int)((i*4) & (DIM-1));
  float4 v = ((const float4*)x)[i];
  ushort4 r;
  r.x = f2b(v.x*sc[c4+0] + sh[c4+0]);
  r.y = f2b(v.y*sc[c4+1] + sh[c4+1]);
  r.z = f2b(v.z*sc[c4+2] + sh[c4+2]);
  r.w = f2b(v.w*sc[c4+3] + sh[c4+3]);
  ((ushort4*)h0)[i] = r;
}

__global__ void count_deg(const void* __restrict__ edge, const int* __restrict__ flag,
                          int* __restrict__ deg) {
  int e = blockIdx.x*blockDim.x + threadIdx.x;
  if (e >= NE) return;
  int d = (*flag) ? (int)((const long long*)edge)[NE + e] : ((const int*)edge)[NE + e];
  atomicAdd(&deg[d], 1);
}

__global__ void deg_bsum(const int* __restrict__ deg, int* __restrict__ bsum) {
  __shared__ int sm[256];
  int i = blockIdx.x*256 + threadIdx.x;
  sm[threadIdx.x] = (i < NN) ? deg[i] : 0;
  __syncthreads();
  for (int off = 128; off > 0; off >>= 1) {
    if (threadIdx.x < off) sm[threadIdx.x] += sm[threadIdx.x + off];
    __syncthreads();
  }
  if (threadIdx.x == 0) bsum[blockIdx.x] = sm[0];
}

__global__ void scan_bsum(const int* __restrict__ bsum, int* __restrict__ boff) {
  __shared__ int sm[256];
  int t = threadIdx.x;
  int v = (t < SCAN_NB) ? bsum[t] : 0;
  sm[t] = v;
  __syncthreads();
  for (int off = 1; off < 256; off <<= 1) {
    int xx = (t >= off) ? sm[t-off] : 0;
    __syncthreads();
    sm[t] += xx;
    __syncthreads();
  }
  if (t < SCAN_NB) boff[t] = sm[t] - v;   // exclusive
}

__global__ void scan_apply(const int* __restrict__ deg, const int* __restrict__ boff,
                           int* __restrict__ row_start, int* __restrict__ cursor) {
  __shared__ int sm[256];
  int t = threadIdx.x;
  int i = blockIdx.x*256 + t;
  int v = (i < NN) ? deg[i] : 0;
  sm[t] = v;
  __syncthreads();
  for (int off = 1; off < 256; off <<= 1) {
    int xx = (t >= off) ? sm[t-off] : 0;
    __syncthreads();
    sm[t] += xx;
    __syncthreads();
  }
  int ex = boff[blockIdx.x] + sm[t] - v;
  if (i < NN) { row_start[i] = ex; cursor[i] = ex; }
  if (i == NN-1) row_start[NN] = ex + v;  // == NE
}

__global__ void scatter_edges(const void* __restrict__ edge, const int* __restrict__ flag,
                              int* __restrict__ cursor, int* __restrict__ csr_src) {
  int e = blockIdx.x*blockDim.x + threadIdx.x;
  if (e >= NE) return;
  int s, d;
  if (*flag) {
    s = (int)((const long long*)edge)[e];
    d = (int)((const long long*)edge)[NE + e];
  } else {
    s = ((const int*)edge)[e];
    d = ((const int*)edge)[NE + e];
  }
  int pos = atomicAdd(&cursor[d], 1);
  csr_src[pos] = s;
}

// one wave per node; 4 lane-groups of 16 each own a different neighbor
// (16B dwordx4 per lane covers the 256B row), index load pipelined one
// iteration ahead; cross-group combine via shfl_xor(16/32).
__global__ __launch_bounds__(256) void aggregate(
    const unsigned short* __restrict__ h, const int* __restrict__ row_start,
    const int* __restrict__ csr_src, unsigned short* __restrict__ out) {
  int node = blockIdx.x*4 + (threadIdx.x >> 6);
  if (node >= NN) return;
  int lane = threadIdx.x & 63;
  int grp = lane >> 4, l15 = lane & 15;
  int p0 = row_start[node], p1 = row_start[node+1];

  float acc[8];
  #pragma unroll
  for (int j = 0; j < 8; ++j) acc[j] = 0.f;

  int p = p0 + grp;
  int s = (p < p1) ? csr_src[p] : -1;
  while (s >= 0) {
    int pn = p + 4;
    int sn = (pn < p1) ? csr_src[pn] : -1;
    uint4 v = *(const uint4*)(h + (size_t)s*128 + l15*8);
    acc[0] += __uint_as_float(v.x << 16);
    acc[1] += __uint_as_float(v.x & 0xffff0000u);
    acc[2] += __uint_as_float(v.y << 16);
    acc[3] += __uint_as_float(v.y & 0xffff0000u);
    acc[4] += __uint_as_float(v.z << 16);
    acc[5] += __uint_as_float(v.z & 0xffff0000u);
    acc[6] += __uint_as_float(v.w << 16);
    acc[7] += __uint_as_float(v.w & 0xffff0000u);
    p = pn; s = sn;
  }

  #pragma unroll
  for (int j = 0; j < 8; ++j) {
    acc[j] += __shfl_xor(acc[j], 16);
    acc[j] += __shfl_xor(acc[j], 32);
  }

  int d = p1 - p0;
  float inv = 1.0f / (float)(d > 1 ? d : 1);
  if (lane < 16) {
    uint4 o;
    o.x = ((unsigned)f2b(acc[1]*inv) << 16) | f2b(acc[0]*inv);
    o.y = ((unsigned)f2b(acc[3]*inv) << 16) | f2b(acc[2]*inv);
    o.z = ((unsigned)f2b(acc[5]*inv) << 16) | f2b(acc[4]*inv);
    o.w = ((unsigned)f2b(acc[7]*inv) << 16) | f2b(acc[6]*inv);
    *(uint4*)(out + (size_t)node*128 + l15*8) = o;
  }
}

// fused SAGE layer: hout = ELU( [agg|root](bf16) @ Wcat^T(bf16) + bias ), MFMA fp32-accum
__global__ __launch_bounds__(256) void sage_mfma(
    const unsigned short* __restrict__ aggb, const unsigned short* __restrict__ rootb,
    const unsigned short* __restrict__ Wcat, const float* __restrict__ bias,
    unsigned short* __restrict__ hout) {
  int t = threadIdx.x;
  int lane = t & 63;
  int w = t >> 6;
  int m0 = blockIdx.x*64 + w*16;
  int l15 = lane & 15, lg = lane >> 4;

  int rowA = m0 + l15; if (rowA > NN-1) rowA = NN-1;
  f32x4 acc[8];
  #pragma unroll
  for (int jf = 0; jf < 8; ++jf) acc[jf] = (f32x4){0.f,0.f,0.f,0.f};

  #pragma unroll
  for (int kc = 0; kc < 8; ++kc) {
    const unsigned short* ab = (kc < 4) ? aggb : rootb;
    bf16x8 a = *(const bf16x8*)(ab + (size_t)rowA*128 + (kc & 3)*32 + 8*lg);
    #pragma unroll
    for (int jf = 0; jf < 8; ++jf) {
      bf16x8 b = *(const bf16x8*)(Wcat + (size_t)(jf*16 + l15)*256 + kc*32 + 8*lg);
      acc[jf] = __builtin_amdgcn_mfma_f32_16x16x32_bf16(a, b, acc[jf], 0, 0, 0);
    }
  }

  #pragma unroll
  for (int jf = 0; jf < 8; ++jf) {
    int col = jf*16 + l15;
    float bj = bias[col];
    #pragma unroll
    for (int r = 0; r < 4; ++r) {
      int node = m0 + 4*lg + r;
      float v = acc[jf][r] + bj;
      v = (v > 0.f) ? v : (expf(v) - 1.0f);    // ELU
      if (node < NN) hout[(size_t)node*128 + col] = f2b(v);
    }
  }
}

__global__ void graph_bounds(const void* __restrict__ batch, const int* __restrict__ flag,
                             int* __restrict__ gstart) {
  int n = blockIdx.x*blockDim.x + threadIdx.x;
  if (n > NN) return;
  bool w = (*flag != 0);
  int bn = NGR, bp = -1;
  if (n < NN) bn = w ? (int)((const long long*)batch)[n]   : ((const int*)batch)[n];
  if (n > 0)  bp = w ? (int)((const long long*)batch)[n-1] : ((const int*)batch)[n-1];
  for (int g = bp + 1; g <= bn; ++g) gstart[g] = n;   // gstart[g] = lower_bound(batch, g)
}

// per-(graph, slice) partial max -> part[g][s][c]; 2048 blocks for parallelism
__global__ void max_pool_partial(const unsigned short* __restrict__ h,
                                 const int* __restrict__ gstart,
                                 float* __restrict__ part) {
  int g = blockIdx.x, s = blockIdx.y, c = threadIdx.x;
  int n0 = gstart[g], n1 = gstart[g+1];
  int cnt = n1 - n0;
  int per = (cnt + MP_SLICES - 1) / MP_SLICES;
  int a = n0 + s*per;
  int b = a + per; if (b > n1) b = n1;
  float m = -INFINITY;
  for (int n = a; n < b; ++n) m = fmaxf(m, b2f(h[(size_t)n*DIM + c]));
  part[((size_t)g*MP_SLICES + s)*DIM + c] = m;
}

__global__ void max_pool_final(const float* __restrict__ part, float* __restrict__ ro) {
  int g = blockIdx.x, c = threadIdx.x;
  float m = -INFINITY;
  #pragma unroll
  for (int s = 0; s < MP_SLICES; ++s)
    m = fmaxf(m, part[((size_t)g*MP_SLICES + s)*DIM + c]);
  ro[g*DIM + c] = m;
}

__global__ void classify(const float* __restrict__ ro,
                         const float* __restrict__ Wc1, const float* __restrict__ bc1,
                         const float* __restrict__ Wc2, const float* __restrict__ bc2,
                         float* __restrict__ out) {
  int g = blockIdx.x, t = threadIdx.x;   // 64 threads
  __shared__ float row[128];
  __shared__ float rv[64];
  row[t]      = ro[g*DIM + t];
  row[t + 64] = ro[g*DIM + 64 + t];
  __syncthreads();
  float acc = bc1[t];
  for (int k = 0; k < 128; ++k) acc += row[k] * Wc1[t*128 + k];
  rv[t] = acc;
  out[1280 + g*64 + t] = acc;            // rv output (second tuple element)
  __syncthreads();
  if (t < 10) {
    float o = bc2[t];
    for (int k = 0; k < 64; ++k) o += rv[k] * Wc2[t*64 + k];
    out[g*10 + t] = o;                   // logits (first tuple element)
  }
}

extern "C" void kernel_launch(void* const* d_in, const int* in_sizes, int n_in,
                              void* d_out, int out_size, void* d_ws, size_t ws_size,
                              hipStream_t stream) {
  const float* x     = (const float*)d_in[0];
  const void*  edge  = d_in[1];
  const void*  batch = d_in[2];
  const float* gamma = (const float*)d_in[3];
  const float* beta  = (const float*)d_in[4];
  const float* W1l   = (const float*)d_in[5];
  const float* b1    = (const float*)d_in[6];
  const float* W1r   = (const float*)d_in[7];
  const float* W2l   = (const float*)d_in[8];
  const float* b2    = (const float*)d_in[9];
  const float* W2r   = (const float*)d_in[10];
  const float* Wc1   = (const float*)d_in[11];
  const float* bc1   = (const float*)d_in[12];
  const float* Wc2   = (const float*)d_in[13];
  const float* bc2   = (const float*)d_in[14];
  char* ws = (char*)d_ws;
  float* out = (float*)d_out;
  if (ws_size < (size_t)WS_NEED) return;

  int*   flag   = (int*)  (ws + OFF_FLAG);
  float* sc     = (float*)(ws + OFF_SCALE);
  float* sh     = (float*)(ws + OFF_SHIFT);
  int*   gstart = (int*)  (ws + OFF_GSTART);
  int*   bsum   = (int*)  (ws + OFF_BSUM);
  int*   boff   = (int*)  (ws + OFF_BOFF);
  float* psum   = (float*)(ws + OFF_PSUM);
  float* psq    = (float*)(ws + OFF_PSQ);
  unsigned short* Wcat1 = (unsigned short*)(ws + OFF_WC1);
  unsigned short* Wcat2 = (unsigned short*)(ws + OFF_WC2);
  float* ro     = (float*)(ws + OFF_RO);
  int*   deg    = (int*)  (ws + OFF_DEG);
  int*   rstart = (int*)  (ws + OFF_RSTART);
  int*   cursor = (int*)  (ws + OFF_CURSOR);
  int*   csr    = (int*)  (ws + OFF_CSR);
  float* part   = (float*)(ws + OFF_PART);
  unsigned short* h0b  = (unsigned short*)(ws + OFF_H0B);
  unsigned short* h1b  = (unsigned short*)(ws + OFF_H1B);
  unsigned short* aggb = (unsigned short*)(ws + OFF_AGGB);
  unsigned short* h2b  = h0b;   // reuse

  probe_width<<<1, 1, 0, stream>>>((const unsigned*)edge, flag);
  pack_weights<<<128, 256, 0, stream>>>(W1l, W1r, Wcat1);
  pack_weights<<<128, 256, 0, stream>>>(W2l, W2r, Wcat2);

  hipMemsetAsync(deg, 0, NN*sizeof(int), stream);
  count_deg<<<(NE+255)/256, 256, 0, stream>>>(edge, flag, deg);
  deg_bsum<<<SCAN_NB, 256, 0, stream>>>(deg, bsum);
  scan_bsum<<<1, 256, 0, stream>>>(bsum, boff);
  scan_apply<<<SCAN_NB, 256, 0, stream>>>(deg, boff, rstart, cursor);
  scatter_edges<<<(NE+255)/256, 256, 0, stream>>>(edge, flag, cursor, csr);

  bn_stats<<<256, 256, 0, stream>>>(x, psum, psq);
  bn_final<<<1, 128, 0, stream>>>(psum, psq, gamma, beta, sc, sh);
  bn_apply<<<(NN*DIM/4 + 255)/256, 256, 0, stream>>>(x, sc, sh, h0b);

  aggregate<<<(NN+3)/4, 256, 0, stream>>>(h0b, rstart, csr, aggb);
  sage_mfma<<<(NN+63)/64, 256, 0, stream>>>(aggb, h0b, Wcat1, b1, h1b);
  aggregate<<<(NN+3)/4, 256, 0, stream>>>(h1b, rstart, csr, aggb);
  sage_mfma<<<(NN+63)/64, 256, 0, stream>>>(aggb, h1b, Wcat2, b2, h2b);

  graph_bounds<<<(NN+1+255)/256, 256, 0, stream>>>(batch, flag, gstart);
  {
    dim3 grid(NGR, MP_SLICES);
    max_pool_partial<<<grid, 128, 0, stream>>>(h2b, gstart, part);
  }
  max_pool_final<<<NGR, 128, 0, stream>>>(part, ro);
  classify<<<NGR, 64, 0, stream>>>(ro, Wc1, bc1, Wc2, bc2, out);
}